// Round 1
// baseline (1500.537 us; speedup 1.0000x reference)
//
#include <hip/hip_runtime.h>
#include <hip/hip_bf16.h>
#include <math.h>

#define HIDDEN 2048
#define INTER 768
#define NE 32
#define TOPK 8
#define T 512
#define TILE_T 16

// ---------------------------------------------------------------------------
// Workspace layout (bytes):
//   [0, 128)            counts[NE]            (zeroed each launch)
//   [1024, 1024+16K)    topw[T*TOPK]  f32     renormalized top-k weights, idx by pair p=t*8+k
//   [17408, +64K)       entries[NE*T] int     pair ids grouped by expert
//   [82944, +12.6MB)    glu[T*TOPK][INTER] f32
// Total ~12.7 MB
// ---------------------------------------------------------------------------
#define WS_TOPW_OFF    1024
#define WS_ENTRIES_OFF (1024 + 16384)
#define WS_GLU_OFF     (1024 + 16384 + 65536)

// ---------------- Router: logits -> top8 -> renorm weights + expert lists ----
__global__ __launch_bounds__(256) void router_kernel(
    const float* __restrict__ x, const float* __restrict__ gw,
    float* __restrict__ topw, int* __restrict__ counts, int* __restrict__ entries)
{
    int t = blockIdx.x;
    const float* xt = x + (size_t)t * HIDDEN;
    __shared__ float logits[NE];

    int e   = threadIdx.x >> 3;   // 0..31, 8 threads per expert
    int sub = threadIdx.x & 7;
    const float* we = gw + (size_t)e * HIDDEN;
    float acc = 0.f;
    for (int h = sub; h < HIDDEN; h += 8) acc += xt[h] * we[h];
    // reduce across the 8 sub-lanes (contiguous lanes within the wave)
    acc += __shfl_down(acc, 4);
    acc += __shfl_down(acc, 2);
    acc += __shfl_down(acc, 1);
    if (sub == 0) logits[e] = acc;
    __syncthreads();

    if (threadIdx.x == 0) {
        float l[NE];
        #pragma unroll
        for (int i = 0; i < NE; ++i) l[i] = logits[i];
        int   bi[TOPK];
        float bv[TOPK];
        for (int k = 0; k < TOPK; ++k) {
            float best = -1e30f; int b = 0;
            for (int i = 0; i < NE; ++i) {
                if (l[i] > best) { best = l[i]; b = i; }
            }
            bi[k] = b; bv[k] = best; l[b] = -1e30f;
        }
        // softmax over top-k == softmax-then-renormalize (denominator cancels)
        float m = bv[0];
        float w[TOPK];
        float s = 0.f;
        for (int k = 0; k < TOPK; ++k) { w[k] = expf(bv[k] - m); s += w[k]; }
        float inv = 1.f / s;
        for (int k = 0; k < TOPK; ++k) {
            int p = t * TOPK + k;
            topw[p] = w[k] * inv;
            int pos = atomicAdd(&counts[bi[k]], 1);
            entries[bi[k] * T + pos] = p;
        }
    }
}

// ---------------- Gate+Up: glu[p, :] = silu(x@Wg) * (x@Wu) per expert tile ---
__global__ __launch_bounds__(256) void gateup_kernel(
    const float* __restrict__ x, const float* __restrict__ Wg, const float* __restrict__ Wu,
    const int* __restrict__ counts, const int* __restrict__ entries,
    float* __restrict__ glu)
{
    int e    = blockIdx.x;
    int tile = blockIdx.y;
    int n     = counts[e];
    int start = tile * TILE_T;
    if (start >= n) return;
    int rows = min(TILE_T, n - start);

    __shared__ float xs[64][TILE_T];   // transposed x tile chunk: xs[h][r]
    __shared__ int   prow[TILE_T];

    int tid = threadIdx.x;
    if (tid < TILE_T) {
        prow[tid] = (tid < rows) ? entries[e * T + start + tid] : -1;
    }

    float accg[3][TILE_T];
    float accu[3][TILE_T];
    #pragma unroll
    for (int c = 0; c < 3; ++c)
        #pragma unroll
        for (int r = 0; r < TILE_T; ++r) { accg[c][r] = 0.f; accu[c][r] = 0.f; }

    const float* wgBase = Wg + (size_t)e * HIDDEN * INTER + tid;
    const float* wuBase = Wu + (size_t)e * HIDDEN * INTER + tid;

    for (int hc = 0; hc < HIDDEN; hc += 64) {
        __syncthreads();
        #pragma unroll
        for (int q = 0; q < 4; ++q) {
            int idx = tid + q * 256;    // 0..1023
            int h = idx & 63;           // coalesced over h in global
            int r = idx >> 6;
            int p = prow[r];
            xs[h][r] = (p >= 0) ? x[(size_t)(p >> 3) * HIDDEN + hc + h] : 0.f;
        }
        __syncthreads();

        const float* wgp = wgBase + (size_t)hc * INTER;
        const float* wup = wuBase + (size_t)hc * INTER;
        for (int h = 0; h < 64; ++h) {
            float wgv[3], wuv[3];
            #pragma unroll
            for (int c = 0; c < 3; ++c) { wgv[c] = wgp[c * 256]; wuv[c] = wup[c * 256]; }
            wgp += INTER; wup += INTER;
            #pragma unroll
            for (int r4 = 0; r4 < TILE_T; r4 += 4) {
                float4 xv = *(const float4*)(&xs[h][r4]);   // uniform addr -> LDS broadcast
                float xr[4] = {xv.x, xv.y, xv.z, xv.w};
                #pragma unroll
                for (int j = 0; j < 4; ++j) {
                    #pragma unroll
                    for (int c = 0; c < 3; ++c) {
                        accg[c][r4 + j] += xr[j] * wgv[c];
                        accu[c][r4 + j] += xr[j] * wuv[c];
                    }
                }
            }
        }
    }

    #pragma unroll
    for (int r = 0; r < TILE_T; ++r) {
        if (r < rows) {
            int p = prow[r];
            #pragma unroll
            for (int c = 0; c < 3; ++c) {
                float g = accg[c][r];
                float u = accu[c][r];
                float s = g / (1.f + expf(-g));   // silu
                glu[(size_t)p * INTER + tid + c * 256] = s * u;
            }
        }
    }
}

// ---------------- Down: out[t,:] += w * (glu[p,:] @ Wd[e])  (atomic combine) -
__global__ __launch_bounds__(256) void down_kernel(
    const float* __restrict__ glu, const float* __restrict__ Wd,
    const int* __restrict__ counts, const int* __restrict__ entries,
    const float* __restrict__ topw, float* __restrict__ out)
{
    int e    = blockIdx.x;
    int tile = blockIdx.y;
    int n     = counts[e];
    int start = tile * TILE_T;
    if (start >= n) return;
    int rows = min(TILE_T, n - start);

    __shared__ float gs[64][TILE_T];   // gs[k][r]
    __shared__ int   prow[TILE_T];
    __shared__ float pw[TILE_T];

    int tid = threadIdx.x;
    if (tid < TILE_T) {
        int p = (tid < rows) ? entries[e * T + start + tid] : -1;
        prow[tid] = p;
        pw[tid]   = (p >= 0) ? topw[p] : 0.f;
    }

    float acco[4][TILE_T];
    #pragma unroll
    for (int c = 0; c < 4; ++c)
        #pragma unroll
        for (int r = 0; r < TILE_T; ++r) acco[c][r] = 0.f;

    int jbase = blockIdx.z * 1024 + tid;   // + c*256, c in 0..3
    const float* wdBase = Wd + (size_t)e * INTER * HIDDEN + jbase;

    for (int kc = 0; kc < INTER; kc += 64) {
        __syncthreads();
        #pragma unroll
        for (int q = 0; q < 4; ++q) {
            int idx = tid + q * 256;
            int k = idx & 63;
            int r = idx >> 6;
            int p = prow[r];
            gs[k][r] = (p >= 0) ? glu[(size_t)p * INTER + kc + k] : 0.f;
        }
        __syncthreads();

        const float* wdp = wdBase + (size_t)kc * HIDDEN;
        for (int k = 0; k < 64; ++k) {
            float wv[4];
            #pragma unroll
            for (int c = 0; c < 4; ++c) wv[c] = wdp[c * 256];
            wdp += HIDDEN;
            #pragma unroll
            for (int r4 = 0; r4 < TILE_T; r4 += 4) {
                float4 gv = *(const float4*)(&gs[k][r4]);
                float gr[4] = {gv.x, gv.y, gv.z, gv.w};
                #pragma unroll
                for (int j = 0; j < 4; ++j) {
                    #pragma unroll
                    for (int c = 0; c < 4; ++c) acco[c][r4 + j] += gr[j] * wv[c];
                }
            }
        }
    }

    #pragma unroll
    for (int r = 0; r < TILE_T; ++r) {
        if (r < rows) {
            int p   = prow[r];
            int tok = p >> 3;
            float wgt = pw[r];
            #pragma unroll
            for (int c = 0; c < 4; ++c) {
                atomicAdd(&out[(size_t)tok * HIDDEN + jbase + c * 256], wgt * acco[c][r]);
            }
        }
    }
}

extern "C" void kernel_launch(void* const* d_in, const int* in_sizes, int n_in,
                              void* d_out, int out_size, void* d_ws, size_t ws_size,
                              hipStream_t stream) {
    const float* x  = (const float*)d_in[0];   // [1,512,2048]
    const float* gw = (const float*)d_in[1];   // [32,2048]
    const float* Wg = (const float*)d_in[2];   // [32,2048,768]
    const float* Wu = (const float*)d_in[3];   // [32,2048,768]
    const float* Wd = (const float*)d_in[4];   // [32,768,2048]
    float* out = (float*)d_out;

    char* ws = (char*)d_ws;
    int*   counts  = (int*)ws;
    float* topw    = (float*)(ws + WS_TOPW_OFF);
    int*   entries = (int*)(ws + WS_ENTRIES_OFF);
    float* glu     = (float*)(ws + WS_GLU_OFF);

    hipMemsetAsync(d_ws, 0, 1024, stream);                               // counts = 0
    hipMemsetAsync(d_out, 0, (size_t)out_size * sizeof(float), stream);  // combine target

    router_kernel<<<T, 256, 0, stream>>>(x, gw, topw, counts, entries);

    dim3 g2(NE, T / TILE_T);        // (32, 32); blocks past counts[e] exit early
    gateup_kernel<<<g2, 256, 0, stream>>>(x, Wg, Wu, counts, entries, glu);

    dim3 g3(NE, T / TILE_T, 2);     // z splits HIDDEN cols into 2 halves of 1024
    down_kernel<<<g3, 256, 0, stream>>>(glu, Wd, counts, entries, topw, out);
}

// Round 2
// 683.787 us; speedup vs baseline: 2.1945x; 2.1945x over previous
//
#include <hip/hip_runtime.h>
#include <math.h>

#define H 2048
#define I 768
#define NE 32
#define TOPK 8
#define T 512

typedef __attribute__((ext_vector_type(4))) float f32x4;
typedef __attribute__((ext_vector_type(8))) short s16x8;

// Workspace layout (bytes)
#define WS_TOPW_OFF    1024                     // float[T*TOPK]
#define WS_ENTRIES_OFF (1024 + 16384)           // int[NE*T]
#define WS_XB_OFF      131072                   // ushort[T*H]      (2 MB)
#define WS_GLU_OFF     (4*1024*1024)            // ushort[T*TOPK*I] (6.3 MB)

__device__ __forceinline__ unsigned int f2bf(float f) {
    unsigned int u = __float_as_uint(f);
    return (u + 0x7FFFu + ((u >> 16) & 1u)) >> 16;   // RNE truncate to bf16 bits
}

// ---------------- x f32 -> bf16 ---------------------------------------------
__global__ __launch_bounds__(256) void convert_x_kernel(
    const float* __restrict__ x, ushort* __restrict__ xb)
{
    int i = (blockIdx.x * 256 + threadIdx.x) * 8;
    float4 a = *(const float4*)(x + i);
    float4 b = *(const float4*)(x + i + 4);
    uint4 o;
    o.x = f2bf(a.x) | (f2bf(a.y) << 16);
    o.y = f2bf(a.z) | (f2bf(a.w) << 16);
    o.z = f2bf(b.x) | (f2bf(b.y) << 16);
    o.w = f2bf(b.z) | (f2bf(b.w) << 16);
    *(uint4*)(xb + i) = o;
}

// ---------------- Router ----------------------------------------------------
__global__ __launch_bounds__(256) void router_kernel(
    const float* __restrict__ x, const float* __restrict__ gw,
    float* __restrict__ topw, int* __restrict__ counts, int* __restrict__ entries)
{
    int t = blockIdx.x;
    const float* xt = x + (size_t)t * H;
    __shared__ float logits[NE];

    int e   = threadIdx.x >> 3;
    int sub = threadIdx.x & 7;
    const float* we = gw + (size_t)e * H;
    float acc = 0.f;
    for (int h = sub; h < H; h += 8) acc += xt[h] * we[h];
    acc += __shfl_down(acc, 4);
    acc += __shfl_down(acc, 2);
    acc += __shfl_down(acc, 1);
    if (sub == 0) logits[e] = acc;
    __syncthreads();

    if (threadIdx.x == 0) {
        float l[NE];
        #pragma unroll
        for (int i2 = 0; i2 < NE; ++i2) l[i2] = logits[i2];
        int bi[TOPK]; float bv[TOPK];
        for (int k = 0; k < TOPK; ++k) {
            float best = -1e30f; int b = 0;
            for (int i2 = 0; i2 < NE; ++i2)
                if (l[i2] > best) { best = l[i2]; b = i2; }
            bi[k] = b; bv[k] = best; l[b] = -1e30f;
        }
        float m = bv[0], s = 0.f, w[TOPK];
        for (int k = 0; k < TOPK; ++k) { w[k] = expf(bv[k] - m); s += w[k]; }
        float inv = 1.f / s;
        for (int k = 0; k < TOPK; ++k) {
            int p = t * TOPK + k;
            topw[p] = w[k] * inv;
            int pos = atomicAdd(&counts[bi[k]], 1);
            entries[bi[k] * T + pos] = p;
        }
    }
}

// ---------------- Gate+Up MFMA: glu[p,:] = silu(x@Wg)*(x@Wu) ----------------
// Tile: M=128 tokens, N=64 cols (per op), BK=64.  4 waves: 2x2 over (M,N),
// each wave 64x32 per op = 4 m-frags x 2 n-frags of 16x16x32 bf16 MFMA.
__global__ __launch_bounds__(256) void gateup_kernel(
    const ushort* __restrict__ xb, const float* __restrict__ Wg, const float* __restrict__ Wu,
    const int* __restrict__ counts, const int* __restrict__ entries,
    ushort* __restrict__ glu)
{
    int e  = blockIdx.x;
    int nt = blockIdx.y;      // 0..11
    int mt = blockIdx.z;      // 0..3
    int n  = counts[e];
    if (mt * 128 >= n) return;

    __shared__ ushort A_lds[128 * 72];   // [row][k], stride 72 bf16 (pad 8)
    __shared__ ushort Bg_lds[64 * 72];   // [n][k] transposed
    __shared__ ushort Bu_lds[64 * 72];
    __shared__ int prow[128];

    int tid = threadIdx.x;
    if (tid < 128) {
        int idx = mt * 128 + tid;
        prow[tid] = (idx < n) ? entries[e * T + idx] : -1;
    }
    __syncthreads();

    int lane = tid & 63;
    int wid  = tid >> 6;
    int wm = wid >> 1, wn = wid & 1;
    int quad = lane >> 4, l16 = lane & 15;

    f32x4 accg[4][2], accu[4][2];
    #pragma unroll
    for (int mi = 0; mi < 4; ++mi)
        #pragma unroll
        for (int ni = 0; ni < 2; ++ni) {
            #pragma unroll
            for (int r = 0; r < 4; ++r) { accg[mi][ni][r] = 0.f; accu[mi][ni][r] = 0.f; }
        }

    const float* wgB = Wg + (size_t)e * H * I + nt * 64;
    const float* wuB = Wu + (size_t)e * H * I + nt * 64;
    int n4 = tid & 15;    // float4 col group for B staging
    int kb = tid >> 4;    // 0..15

    for (int hc = 0; hc < H; hc += 64) {
        // --- stage A: 128 rows x 64 bf16, gathered token rows ---
        #pragma unroll
        for (int s = 0; s < 4; ++s) {
            int c = tid + s * 256;            // 0..1023 chunks of 8 bf16
            int r = c >> 3, ch = c & 7;
            int p = prow[r];
            int4 v = make_int4(0, 0, 0, 0);
            if (p >= 0)
                v = *(const int4*)(xb + (size_t)(p >> 3) * H + hc + ch * 8);
            *(int4*)&A_lds[r * 72 + ch * 8] = v;
        }
        // --- stage B (transpose to [n][k], cvt f32->bf16 in-register) ---
        #pragma unroll
        for (int q = 0; q < 2; ++q) {
            int k = kb * 2 + q * 32;          // even k
            const float* g0 = wgB + (size_t)(hc + k) * I + n4 * 4;
            const float* u0 = wuB + (size_t)(hc + k) * I + n4 * 4;
            float4 ga = *(const float4*)g0;
            float4 gb = *(const float4*)(g0 + I);
            float4 ua = *(const float4*)u0;
            float4 ub = *(const float4*)(u0 + I);
            float gax[4] = {ga.x, ga.y, ga.z, ga.w};
            float gbx[4] = {gb.x, gb.y, gb.z, gb.w};
            float uax[4] = {ua.x, ua.y, ua.z, ua.w};
            float ubx[4] = {ub.x, ub.y, ub.z, ub.w};
            #pragma unroll
            for (int i2 = 0; i2 < 4; ++i2) {
                *(unsigned int*)&Bg_lds[(n4 * 4 + i2) * 72 + k] = f2bf(gax[i2]) | (f2bf(gbx[i2]) << 16);
                *(unsigned int*)&Bu_lds[(n4 * 4 + i2) * 72 + k] = f2bf(uax[i2]) | (f2bf(ubx[i2]) << 16);
            }
        }
        __syncthreads();
        // --- MFMA: 2 k-steps of K=32 ---
        #pragma unroll
        for (int s = 0; s < 2; ++s) {
            int ko = s * 32 + quad * 8;
            s16x8 af[4];
            #pragma unroll
            for (int mi = 0; mi < 4; ++mi)
                af[mi] = *(const s16x8*)&A_lds[(wm * 64 + mi * 16 + l16) * 72 + ko];
            #pragma unroll
            for (int ni = 0; ni < 2; ++ni) {
                s16x8 bg = *(const s16x8*)&Bg_lds[(wn * 32 + ni * 16 + l16) * 72 + ko];
                s16x8 bu = *(const s16x8*)&Bu_lds[(wn * 32 + ni * 16 + l16) * 72 + ko];
                #pragma unroll
                for (int mi = 0; mi < 4; ++mi) {
                    accg[mi][ni] = __builtin_amdgcn_mfma_f32_16x16x32_bf16(af[mi], bg, accg[mi][ni], 0, 0, 0);
                    accu[mi][ni] = __builtin_amdgcn_mfma_f32_16x16x32_bf16(af[mi], bu, accu[mi][ni], 0, 0, 0);
                }
            }
        }
        __syncthreads();
    }

    // --- epilogue: silu(g)*u -> glu bf16 ---
    #pragma unroll
    for (int mi = 0; mi < 4; ++mi) {
        #pragma unroll
        for (int reg = 0; reg < 4; ++reg) {
            int r = wm * 64 + mi * 16 + quad * 4 + reg;
            int p = prow[r];
            if (p >= 0) {
                size_t base = (size_t)p * I + nt * 64 + wn * 32;
                #pragma unroll
                for (int ni = 0; ni < 2; ++ni) {
                    float g = accg[mi][ni][reg];
                    float u = accu[mi][ni][reg];
                    float sv = g / (1.f + __expf(-g)) * u;
                    glu[base + ni * 16 + l16] = (ushort)f2bf(sv);
                }
            }
        }
    }
}

// ---------------- Down MFMA: out[t,:] += topw[p] * (glu[p,:] @ Wd[e]) -------
__global__ __launch_bounds__(256) void down_kernel(
    const ushort* __restrict__ glu, const float* __restrict__ Wd,
    const int* __restrict__ counts, const int* __restrict__ entries,
    const float* __restrict__ topw, float* __restrict__ out)
{
    int e  = blockIdx.x;
    int nt = blockIdx.y;      // 0..31 over H cols
    int mt = blockIdx.z;      // 0..3
    int n  = counts[e];
    if (mt * 128 >= n) return;

    __shared__ ushort A_lds[128 * 72];
    __shared__ ushort B_lds[64 * 72];
    __shared__ int   prow[128];
    __shared__ float pw[128];

    int tid = threadIdx.x;
    if (tid < 128) {
        int idx = mt * 128 + tid;
        int p = (idx < n) ? entries[e * T + idx] : -1;
        prow[tid] = p;
        pw[tid]   = (p >= 0) ? topw[p] : 0.f;
    }
    __syncthreads();

    int lane = tid & 63;
    int wid  = tid >> 6;
    int wm = wid >> 1, wn = wid & 1;
    int quad = lane >> 4, l16 = lane & 15;

    f32x4 acc[4][2];
    #pragma unroll
    for (int mi = 0; mi < 4; ++mi)
        #pragma unroll
        for (int ni = 0; ni < 2; ++ni) {
            #pragma unroll
            for (int r = 0; r < 4; ++r) acc[mi][ni][r] = 0.f;
        }

    const float* wdB = Wd + (size_t)e * I * H + nt * 64;
    int n4 = tid & 15;
    int kb = tid >> 4;

    for (int kc = 0; kc < I; kc += 64) {
        #pragma unroll
        for (int s = 0; s < 4; ++s) {
            int c = tid + s * 256;
            int r = c >> 3, ch = c & 7;
            int p = prow[r];
            int4 v = make_int4(0, 0, 0, 0);
            if (p >= 0)
                v = *(const int4*)(glu + (size_t)p * I + kc + ch * 8);
            *(int4*)&A_lds[r * 72 + ch * 8] = v;
        }
        #pragma unroll
        for (int q = 0; q < 2; ++q) {
            int k = kb * 2 + q * 32;
            const float* d0 = wdB + (size_t)(kc + k) * H + n4 * 4;
            float4 da = *(const float4*)d0;
            float4 db = *(const float4*)(d0 + H);
            float dax[4] = {da.x, da.y, da.z, da.w};
            float dbx[4] = {db.x, db.y, db.z, db.w};
            #pragma unroll
            for (int i2 = 0; i2 < 4; ++i2)
                *(unsigned int*)&B_lds[(n4 * 4 + i2) * 72 + k] = f2bf(dax[i2]) | (f2bf(dbx[i2]) << 16);
        }
        __syncthreads();
        #pragma unroll
        for (int s = 0; s < 2; ++s) {
            int ko = s * 32 + quad * 8;
            s16x8 af[4];
            #pragma unroll
            for (int mi = 0; mi < 4; ++mi)
                af[mi] = *(const s16x8*)&A_lds[(wm * 64 + mi * 16 + l16) * 72 + ko];
            #pragma unroll
            for (int ni = 0; ni < 2; ++ni) {
                s16x8 bf = *(const s16x8*)&B_lds[(wn * 32 + ni * 16 + l16) * 72 + ko];
                #pragma unroll
                for (int mi = 0; mi < 4; ++mi)
                    acc[mi][ni] = __builtin_amdgcn_mfma_f32_16x16x32_bf16(af[mi], bf, acc[mi][ni], 0, 0, 0);
            }
        }
        __syncthreads();
    }

    #pragma unroll
    for (int mi = 0; mi < 4; ++mi) {
        #pragma unroll
        for (int reg = 0; reg < 4; ++reg) {
            int r = wm * 64 + mi * 16 + quad * 4 + reg;
            int p = prow[r];
            if (p >= 0) {
                int tok = p >> 3;
                float wgt = pw[r];
                size_t base = (size_t)tok * H + nt * 64 + wn * 32;
                #pragma unroll
                for (int ni = 0; ni < 2; ++ni)
                    atomicAdd(&out[base + ni * 16 + l16], wgt * acc[mi][ni][reg]);
            }
        }
    }
}

extern "C" void kernel_launch(void* const* d_in, const int* in_sizes, int n_in,
                              void* d_out, int out_size, void* d_ws, size_t ws_size,
                              hipStream_t stream) {
    const float* x  = (const float*)d_in[0];
    const float* gw = (const float*)d_in[1];
    const float* Wg = (const float*)d_in[2];
    const float* Wu = (const float*)d_in[3];
    const float* Wd = (const float*)d_in[4];
    float* out = (float*)d_out;

    char* ws = (char*)d_ws;
    int*    counts  = (int*)ws;
    float*  topw    = (float*)(ws + WS_TOPW_OFF);
    int*    entries = (int*)(ws + WS_ENTRIES_OFF);
    ushort* xb      = (ushort*)(ws + WS_XB_OFF);
    ushort* glu     = (ushort*)(ws + WS_GLU_OFF);

    hipMemsetAsync(d_ws, 0, 1024, stream);                               // counts
    hipMemsetAsync(d_out, 0, (size_t)out_size * sizeof(float), stream);  // combine target

    convert_x_kernel<<<T * H / (256 * 8), 256, 0, stream>>>(x, xb);
    router_kernel<<<T, 256, 0, stream>>>(x, gw, topw, counts, entries);

    dim3 g2(NE, I / 64, 4);
    gateup_kernel<<<g2, 256, 0, stream>>>(xb, Wg, Wu, counts, entries, glu);

    dim3 g3(NE, H / 64, 4);
    down_kernel<<<g3, 256, 0, stream>>>(glu, Wd, counts, entries, topw, out);
}